// Round 1
// baseline (468.417 us; speedup 1.0000x reference)
//
#include <hip/hip_runtime.h>
#include <stdint.h>

// RoleModulator: out[b,s,e] = tanh( sum_d H[b,s,d]*W[role_b,d,e] + bias[role_b,e] ) * scale[role_b]
// B=8, S=2048, D=2048, R=4. bf16 MFMA (16x16x32), fp32 accum, tanh epilogue.

#define BDIM 8
#define SDIM 2048
#define DDIM 2048
#define RDIM 4

typedef __attribute__((ext_vector_type(8))) short bf16x8;   // 8 bf16 (4 VGPRs)
typedef __attribute__((ext_vector_type(4))) float f32x4;    // MFMA accumulator

typedef unsigned int uint32;
typedef unsigned short ushort16_t;

__device__ __forceinline__ unsigned short f2bf(float f) {
    uint32 u = __float_as_uint(f);
    u += 0x7fffu + ((u >> 16) & 1u);   // round-to-nearest-even
    return (unsigned short)(u >> 16);
}
__device__ __forceinline__ uint32 pack2(float lo, float hi) {
    return (uint32)f2bf(lo) | ((uint32)f2bf(hi) << 16);
}

// ---------------- fast-path pre-conversion kernels ----------------

// H fp32 -> bf16, straight copy (vectorized float4 -> 4x bf16)
__global__ __launch_bounds__(256) void cvt_h_kernel(const float* __restrict__ h,
                                                    unsigned short* __restrict__ o, int n4) {
    int i = blockIdx.x * blockDim.x + threadIdx.x;
    int stride = gridDim.x * blockDim.x;
    for (; i < n4; i += stride) {
        float4 v = reinterpret_cast<const float4*>(h)[i];
        uint2 p;
        p.x = pack2(v.x, v.y);
        p.y = pack2(v.z, v.w);
        reinterpret_cast<uint2*>(o)[i] = p;
    }
}

// W[r][d][e] fp32 -> Wt[r][e][d] bf16 (transpose so GEMM B-operand is [n][k] row-major)
__global__ __launch_bounds__(256) void cvt_wt_kernel(const float* __restrict__ w,
                                                     unsigned short* __restrict__ o) {
    __shared__ unsigned short tile[32][33];   // +1 pad: conflict-free transpose
    int r = blockIdx.z;
    int e0 = blockIdx.x * 32, d0 = blockIdx.y * 32;
    const float* wr = w + (size_t)r * DDIM * DDIM;
    unsigned short* orr = o + (size_t)r * DDIM * DDIM;
    #pragma unroll
    for (int i = threadIdx.y; i < 32; i += 8)
        tile[i][threadIdx.x] = f2bf(wr[(size_t)(d0 + i) * DDIM + e0 + threadIdx.x]);
    __syncthreads();
    #pragma unroll
    for (int i = threadIdx.y; i < 32; i += 8)
        orr[(size_t)(e0 + i) * DDIM + d0 + threadIdx.x] = tile[threadIdx.x][i];
}

// ---------------- GEMM ----------------
// 128x128 tile, BK=32, 4 waves (2x2), each wave 64x64 = 4x4 fragments of 16x16x32 MFMA.
// PRE=true : A = bf16 H [B,S,D], B = bf16 Wt [R,E,D]; global_load_lds staging, linear LDS rows (64 B).
// PRE=false: A = fp32 H, B = fp32 W [R,D,E]; reg-staged fp32->bf16 convert, padded LDS rows (80 B).

template <bool PRE>
__global__ __launch_bounds__(256, 2) void role_gemm(
    const void* __restrict__ Ap,
    const void* __restrict__ Bp,
    const float* __restrict__ onehot,   // [B,R]
    const float* __restrict__ bias,     // [R,D]
    const float* __restrict__ scales,   // [R]
    float* __restrict__ out)            // [B,S,D]
{
    constexpr int BK = 32;
    constexpr int NT = DDIM / BK;                 // 64 K-steps
    constexpr int ROWB = PRE ? (BK * 2) : (BK * 2 + 16);   // LDS row stride bytes: 64 / 80
    constexpr int TILEB = 128 * ROWB;             // one A or B tile
    __shared__ char lds[2 * 2 * 128 * (PRE ? 64 : 80)];

    const unsigned tid = threadIdx.x;
    const int l = tid & 63;
    const int w = tid >> 6;
    const int wm = w >> 1, wn = w & 1;
    const int fr = l & 15;     // fragment row(A)/col(B,C)
    const int fq = l >> 4;     // k-chunk / C row-quad

    // block -> (batch, tile) with XCD-bijective swizzle (2048 % 8 == 0)
    int bid = blockIdx.x;
    int swz = (bid & 7) * 256 + (bid >> 3);
    int batch = swz >> 8;
    int tt = swz & 255;
    int row0 = (tt >> 4) * 128;   // s-tile base
    int n0 = (tt & 15) * 128;     // e-tile base

    // role select from one-hot
    int role = 0;
    #pragma unroll
    for (int r = 1; r < RDIM; ++r) role = (onehot[batch * RDIM + r] > 0.5f) ? r : role;

    f32x4 acc[4][4];
    #pragma unroll
    for (int a = 0; a < 4; ++a)
        #pragma unroll
        for (int b2 = 0; b2 < 4; ++b2)
            #pragma unroll
            for (int r = 0; r < 4; ++r) acc[a][b2][r] = 0.0f;

    // ---- compute one K-step from LDS buffer p ----
    auto compute = [&](int p) {
        const char* as = lds + p * (2 * TILEB);
        const char* bs = as + TILEB;
        bf16x8 af[4], bf[4];
        #pragma unroll
        for (int a = 0; a < 4; ++a)
            af[a] = *reinterpret_cast<const bf16x8*>(as + (wm * 64 + a * 16 + fr) * ROWB + fq * 16);
        #pragma unroll
        for (int b2 = 0; b2 < 4; ++b2)
            bf[b2] = *reinterpret_cast<const bf16x8*>(bs + (wn * 64 + b2 * 16 + fr) * ROWB + fq * 16);
        #pragma unroll
        for (int a = 0; a < 4; ++a)
            #pragma unroll
            for (int b2 = 0; b2 < 4; ++b2)
                acc[a][b2] = __builtin_amdgcn_mfma_f32_16x16x32_bf16(af[a], bf[b2], acc[a][b2], 0, 0, 0);
    };

    if constexpr (PRE) {
        const unsigned short* A = (const unsigned short*)Ap + (size_t)batch * SDIM * DDIM;
        const unsigned short* Bb = (const unsigned short*)Bp + (size_t)role * DDIM * DDIM;

        // stage tile (k0) into buffer p via global_load_lds width=16
        auto stage = [&](int p, int k0) {
            char* as = lds + p * (2 * TILEB);
            char* bs = as + TILEB;
            #pragma unroll
            for (int j = 0; j < 2; ++j) {
                int c = j * 256 + (int)tid;            // 16B chunk id, 512 per tile
                int crow = c >> 2, ck = (c & 3) * 8;   // row, bf16 k-offset
                const unsigned short* srca = A + (size_t)(row0 + crow) * DDIM + (k0 + ck);
                char* dsta = as + (j * 256 + (int)(tid & 192)) * 16;  // wave-uniform base
                __builtin_amdgcn_global_load_lds(
                    (const __attribute__((address_space(1))) void*)srca,
                    (__attribute__((address_space(3))) void*)dsta, 16, 0, 0);
                const unsigned short* srcb = Bb + (size_t)(n0 + crow) * DDIM + (k0 + ck);
                char* dstb = bs + (j * 256 + (int)(tid & 192)) * 16;
                __builtin_amdgcn_global_load_lds(
                    (const __attribute__((address_space(1))) void*)srcb,
                    (__attribute__((address_space(3))) void*)dstb, 16, 0, 0);
            }
        };

        stage(0, 0);
        __syncthreads();
        for (int t = 0; t < NT; ++t) {
            if (t + 1 < NT) stage((t + 1) & 1, (t + 1) * BK);
            compute(t & 1);
            __syncthreads();   // drains vmcnt -> next buffer ready
        }
    } else {
        const float* A = (const float*)Ap + (size_t)batch * SDIM * DDIM;
        const float* Bb = (const float*)Bp + (size_t)role * DDIM * DDIM;

        const int am = (int)(tid >> 3);          // 0..31
        const int ak = (int)(tid & 7) * 4;       // 0..28
        const int bn = (int)(tid & 127);         // 0..127
        const int bk0 = (int)(tid >> 7) * 4;     // 0 or 4

        float4 ar[4];
        float br[16];

        auto loadregs = [&](int k0) {
            #pragma unroll
            for (int i = 0; i < 4; ++i)
                ar[i] = *reinterpret_cast<const float4*>(A + (size_t)(row0 + am + 32 * i) * DDIM + k0 + ak);
            #pragma unroll
            for (int i = 0; i < 4; ++i)
                #pragma unroll
                for (int j = 0; j < 4; ++j)
                    br[i * 4 + j] = Bb[(size_t)(k0 + bk0 + 8 * i + j) * DDIM + n0 + bn];
        };
        auto writelds = [&](int p) {
            char* as = lds + p * (2 * TILEB);
            char* bs = as + TILEB;
            #pragma unroll
            for (int i = 0; i < 4; ++i) {
                uint2 u;
                u.x = pack2(ar[i].x, ar[i].y);
                u.y = pack2(ar[i].z, ar[i].w);
                *reinterpret_cast<uint2*>(as + (am + 32 * i) * ROWB + ak * 2) = u;
            }
            #pragma unroll
            for (int i = 0; i < 4; ++i) {
                uint2 u;
                u.x = pack2(br[i * 4 + 0], br[i * 4 + 1]);
                u.y = pack2(br[i * 4 + 2], br[i * 4 + 3]);
                *reinterpret_cast<uint2*>(bs + bn * ROWB + (bk0 + 8 * i) * 2) = u;
            }
        };

        loadregs(0);
        writelds(0);
        __syncthreads();
        for (int t = 0; t < NT; ++t) {
            if (t + 1 < NT) loadregs((t + 1) * BK);
            compute(t & 1);
            if (t + 1 < NT) writelds((t + 1) & 1);
            __syncthreads();
        }
    }

    // ---- epilogue: bias + tanh + scale, fp32 store ----
    float sc = scales[role];
    const float* bp2 = bias + (size_t)role * DDIM;
    float* outb = out + ((size_t)batch * SDIM + row0) * DDIM + n0;
    #pragma unroll
    for (int a = 0; a < 4; ++a) {
        #pragma unroll
        for (int b2 = 0; b2 < 4; ++b2) {
            int col = wn * 64 + b2 * 16 + fr;
            float bb = bp2[n0 + col];
            #pragma unroll
            for (int r = 0; r < 4; ++r) {
                int row = wm * 64 + a * 16 + fq * 4 + r;
                outb[(size_t)row * DDIM + col] = tanhf(acc[a][b2][r] + bb) * sc;
            }
        }
    }
}

extern "C" void kernel_launch(void* const* d_in, const int* in_sizes, int n_in,
                              void* d_out, int out_size, void* d_ws, size_t ws_size,
                              hipStream_t stream) {
    const float* hidden = (const float*)d_in[0];   // [B,S,D]
    const float* onehot = (const float*)d_in[1];   // [B,R]
    const float* W      = (const float*)d_in[2];   // [R,D,D]
    const float* bias   = (const float*)d_in[3];   // [R,D]
    const float* scales = (const float*)d_in[4];   // [R]
    float* out = (float*)d_out;

    const size_t needH = (size_t)BDIM * SDIM * DDIM * 2;   // 67,108,864 B
    const size_t needW = (size_t)RDIM * DDIM * DDIM * 2;   // 33,554,432 B

    if (d_ws != nullptr && ws_size >= needH + needW) {
        unsigned short* Hbf = (unsigned short*)d_ws;
        unsigned short* Wt  = (unsigned short*)((char*)d_ws + needH);
        cvt_h_kernel<<<2048, 256, 0, stream>>>(hidden, Hbf, BDIM * SDIM * DDIM / 4);
        cvt_wt_kernel<<<dim3(DDIM / 32, DDIM / 32, RDIM), dim3(32, 8), 0, stream>>>(W, Wt);
        role_gemm<true><<<2048, 256, 0, stream>>>(Hbf, Wt, onehot, bias, scales, out);
    } else {
        role_gemm<false><<<2048, 256, 0, stream>>>(hidden, W, onehot, bias, scales, out);
    }
}

// Round 2
// 404.648 us; speedup vs baseline: 1.1576x; 1.1576x over previous
//
#include <hip/hip_runtime.h>
#include <stdint.h>

// RoleModulator: out[b,s,e] = tanh( sum_d H[b,s,d]*W[role_b,d,e] + bias[role_b,e] ) * scale[role_b]
// B=8, S=2048, D=2048, R=4. bf16 MFMA 16x16x32, fp32 accum.
// Fast path: fp32->bf16 pre-convert (H straight, W transposed), then 256x256
// 8-phase pipelined GEMM (T1 XCD swizzle, T2 LDS xor-swizzle, T3/T4 counted
// vmcnt, T5 setprio) per the m201 template.

#define BDIM 8
#define SDIM 2048
#define DDIM 2048
#define RDIM 4

typedef __attribute__((ext_vector_type(8))) short bf16x8;   // 8 bf16 (4 VGPRs)
typedef __attribute__((ext_vector_type(4))) float f32x4;    // MFMA accumulator
typedef unsigned int uint32;

__device__ __forceinline__ unsigned short f2bf(float f) {
    uint32 u = __float_as_uint(f);
    u += 0x7fffu + ((u >> 16) & 1u);   // round-to-nearest-even
    return (unsigned short)(u >> 16);
}
__device__ __forceinline__ uint32 pack2(float lo, float hi) {
    return (uint32)f2bf(lo) | ((uint32)f2bf(hi) << 16);
}
// overflow-safe fast tanh: t = sign(x) * (1-e)/(1+e), e = exp(-2|x|) in (0,1]
__device__ __forceinline__ float fast_tanh(float x) {
    float ax = __builtin_fabsf(x);
    float e = __expf(-2.0f * ax);
    float t = (1.0f - e) * __builtin_amdgcn_rcpf(1.0f + e);
    return __builtin_copysignf(t, x);
}

// ---------------- pre-conversion kernels ----------------

// H fp32 -> bf16 straight copy, 32B loads / 16B stores per lane
__global__ __launch_bounds__(256) void cvt_h_kernel(const float* __restrict__ h,
                                                    unsigned short* __restrict__ o, int n8) {
    int i = blockIdx.x * blockDim.x + threadIdx.x;
    int stride = gridDim.x * blockDim.x;
    for (; i < n8; i += stride) {
        float4 v0 = reinterpret_cast<const float4*>(h)[2 * i];
        float4 v1 = reinterpret_cast<const float4*>(h)[2 * i + 1];
        uint4 p;
        p.x = pack2(v0.x, v0.y);
        p.y = pack2(v0.z, v0.w);
        p.z = pack2(v1.x, v1.y);
        p.w = pack2(v1.z, v1.w);
        reinterpret_cast<uint4*>(o)[i] = p;
    }
}

// W[r][d][e] fp32 -> Wt[r][e][d] bf16 (transpose: GEMM B-operand is [n][k] row-major)
__global__ __launch_bounds__(256) void cvt_wt_kernel(const float* __restrict__ w,
                                                     unsigned short* __restrict__ o) {
    __shared__ unsigned short tile[32][33];   // +1 pad: conflict-free transpose
    int r = blockIdx.z;
    int e0 = blockIdx.x * 32, d0 = blockIdx.y * 32;
    const float* wr = w + (size_t)r * DDIM * DDIM;
    unsigned short* orr = o + (size_t)r * DDIM * DDIM;
    #pragma unroll
    for (int i = threadIdx.y; i < 32; i += 8)
        tile[i][threadIdx.x] = f2bf(wr[(size_t)(d0 + i) * DDIM + e0 + threadIdx.x]);
    __syncthreads();
    #pragma unroll
    for (int i = threadIdx.y; i < 32; i += 8)
        orr[(size_t)(e0 + i) * DDIM + d0 + threadIdx.x] = tile[threadIdx.x][i];
}

// ---------------- 256x256 8-phase GEMM (fast path) ----------------
// 512 threads = 8 waves (2M x 4N); per-wave 128x64 output = 8x4 frags 16x16.
// BK=64 (2 MFMA k-steps). LDS per buffer: A[256][64] + B[256][64] bf16 = 64KB;
// 2 buffers = 128KB (dynamic). Halves = 128 rows (16KB), staged one per phase.
// Swizzle: logical byte P -> lds byte P ^ ((row&7)<<4); global_load_lds writes
// linearly, so the SOURCE k-chunk is pre-permuted (kc ^ (row&7)); reads XOR.

__global__ __launch_bounds__(512, 2) void role_gemm8(
    const unsigned short* __restrict__ Hb,   // [B,S,D] bf16
    const unsigned short* __restrict__ Wt,   // [R,E,D] bf16
    const float* __restrict__ onehot,        // [B,R]
    const float* __restrict__ bias,          // [R,D]
    const float* __restrict__ scales,        // [R]
    float* __restrict__ out)                 // [B,S,D] fp32
{
    constexpr int NT = DDIM / 64;            // 32 K-tiles
    extern __shared__ char lds[];

    const int tid = threadIdx.x;
    const int l = tid & 63;
    const int wv = tid >> 6;      // 0..7
    const int wm = wv >> 2;       // 0..1  (M half)
    const int wn = wv & 3;        // 0..3  (N quarter)
    const int fr = l & 15;
    const int fq = l >> 4;
    const int l7 = l & 7;
    const int colx0 = ((fq ^ l7) << 4);          // ks=0 swizzled 16B col
    const int colx1 = (((4 + fq) ^ l7) << 4);    // ks=1

    // T1: XCD-bijective swizzle (512 blocks, 512%8==0)
    int bid = blockIdx.x;
    int swz = (bid & 7) * 64 + (bid >> 3);
    int batch = swz >> 6;         // 0..7 (one batch per XCD chunk)
    int tt = swz & 63;
    int row0 = (tt >> 3) * 256;
    int n0 = (tt & 7) * 256;

    int role = 0;
    #pragma unroll
    for (int r = 1; r < RDIM; ++r) role = (onehot[batch * RDIM + r] > 0.5f) ? r : role;

    const unsigned short* A = Hb + (size_t)batch * SDIM * DDIM;
    const unsigned short* Bw = Wt + (size_t)role * DDIM * DDIM;

    f32x4 acc[8][4];
    #pragma unroll
    for (int m = 0; m < 8; ++m)
        #pragma unroll
        for (int n = 0; n < 4; ++n)
            #pragma unroll
            for (int j = 0; j < 4; ++j) acc[m][n][j] = 0.0f;

    bf16x8 aR[4][2];      // current m-quadrant A frags
    bf16x8 bQ0[2][2];     // n-quadrant 0 B frags (kept live across the tile)
    bf16x8 bQ1[2][2];     // n-quadrant 1

    // stage one half-tile: kind 0=A,1=B; buffer d; half h; K-tile T. 2 loads/thread.
    auto stage_half = [&](int d, int kind, int h, int T) {
        const unsigned short* sb = kind ? Bw : A;
        int rowbase = (kind ? n0 : row0) + h * 128;
        char* base = lds + d * 65536 + kind * 32768 + h * 16384;
        #pragma unroll
        for (int j = 0; j < 2; ++j) {
            int c = j * 512 + tid;               // 16B chunk 0..1023
            int r = c >> 3, kc = c & 7;
            int kcs = kc ^ (r & 7);              // inverse-swizzled source k-chunk
            const unsigned short* src = sb + (size_t)(rowbase + r) * DDIM + T * 64 + kcs * 8;
            char* dst = base + ((j * 512 + (tid & 0x1C0)) << 4);   // wave-uniform base
            __builtin_amdgcn_global_load_lds(
                (const __attribute__((address_space(1))) void*)src,
                (__attribute__((address_space(3))) void*)dst, 16, 0, 0);
        }
    };

    auto loadA = [&](int d, int mq) {
        const char* ab = lds + d * 65536;
        #pragma unroll
        for (int mf = 0; mf < 4; ++mf) {
            int rb = (wm * 128 + (mq * 4 + mf) * 16 + fr) * 128;
            aR[mf][0] = *reinterpret_cast<const bf16x8*>(ab + rb + colx0);
            aR[mf][1] = *reinterpret_cast<const bf16x8*>(ab + rb + colx1);
        }
    };
    auto loadB = [&](int d, int nq, bf16x8 (&bR)[2][2]) {
        const char* bb = lds + d * 65536 + 32768;
        #pragma unroll
        for (int nf = 0; nf < 2; ++nf) {
            int rb = (wn * 64 + (nq * 2 + nf) * 16 + fr) * 128;
            bR[nf][0] = *reinterpret_cast<const bf16x8*>(bb + rb + colx0);
            bR[nf][1] = *reinterpret_cast<const bf16x8*>(bb + rb + colx1);
        }
    };
    auto mmaQ = [&](int mq, int nq, bf16x8 (&bR)[2][2]) {
        __builtin_amdgcn_s_setprio(1);
        #pragma unroll
        for (int mf = 0; mf < 4; ++mf)
            #pragma unroll
            for (int nf = 0; nf < 2; ++nf)
                #pragma unroll
                for (int ks = 0; ks < 2; ++ks)
                    acc[mq * 4 + mf][nq * 2 + nf] = __builtin_amdgcn_mfma_f32_16x16x32_bf16(
                        aR[mf][ks], bR[nf][ks], acc[mq * 4 + mf][nq * 2 + nf], 0, 0, 0);
        __builtin_amdgcn_s_setprio(0);
    };

    // ---- prologue: stage tile0 fully + tile1 {B0,B1,A0}; FIFO matches steady state
    stage_half(0, 1, 0, 0); stage_half(0, 1, 1, 0);
    stage_half(0, 0, 0, 0); stage_half(0, 0, 1, 0);
    stage_half(1, 1, 0, 1); stage_half(1, 1, 1, 1);
    stage_half(1, 0, 0, 1);
    asm volatile("s_waitcnt vmcnt(6)" ::: "memory");   // tile0's 8 loads landed
    __builtin_amdgcn_s_barrier();

    // ---- main loop: 4 phases per K-tile; stages one half-tile/phase,
    //      each exactly one phase after that half's last LDS read.
    for (int t = 0; t < NT; ++t) {
        const int d = t & 1, e = d ^ 1;
        // q0: read A(mq0)+B(nq0); stage A-half1(t+1) -> buf e
        loadA(d, 0);
        loadB(d, 0, bQ0);
        if (t + 1 < NT) stage_half(e, 0, 1, t + 1);
        __builtin_amdgcn_s_barrier();
        asm volatile("s_waitcnt lgkmcnt(0)" ::: "memory");
        mmaQ(0, 0, bQ0);
        __builtin_amdgcn_s_barrier();
        // q1: read B(nq1); stage B-half0(t+2) -> buf d (B-half0 last read q0)
        loadB(d, 1, bQ1);
        if (t + 2 < NT) stage_half(d, 1, 0, t + 2);
        __builtin_amdgcn_s_barrier();
        asm volatile("s_waitcnt lgkmcnt(0)" ::: "memory");
        mmaQ(0, 1, bQ1);
        __builtin_amdgcn_s_barrier();
        // q2: read A(mq1); stage B-half1(t+2) (last read q1)
        loadA(d, 1);
        if (t + 2 < NT) stage_half(d, 1, 1, t + 2);
        __builtin_amdgcn_s_barrier();
        asm volatile("s_waitcnt lgkmcnt(0)" ::: "memory");
        mmaQ(1, 1, bQ1);
        __builtin_amdgcn_s_barrier();
        // q3: stage A-half0(t+2) (last read q2); MFMA reuses bQ0 regs
        if (t + 2 < NT) stage_half(d, 0, 0, t + 2);
        __builtin_amdgcn_s_barrier();
        mmaQ(1, 0, bQ0);
        // counted drain: A-half1(t+1) staged at q0 has 3 half-tiles (6 loads) after it
        if (t < NT - 2) { asm volatile("s_waitcnt vmcnt(6)" ::: "memory"); }
        else            { asm volatile("s_waitcnt vmcnt(0)" ::: "memory"); }
        __builtin_amdgcn_s_barrier();
    }

    // ---- epilogue: bias + tanh + scale, fp32 store
    float sc = scales[role];
    const float* bp = bias + (size_t)role * DDIM;
    float* ob = out + ((size_t)batch * SDIM + row0 + wm * 128) * DDIM + n0 + wn * 64;
    #pragma unroll
    for (int mfg = 0; mfg < 8; ++mfg) {
        #pragma unroll
        for (int nfg = 0; nfg < 4; ++nfg) {
            int col = nfg * 16 + fr;
            float bb = bp[n0 + wn * 64 + col];
            #pragma unroll
            for (int j = 0; j < 4; ++j) {
                int row = mfg * 16 + fq * 4 + j;
                ob[(size_t)row * DDIM + col] = fast_tanh(acc[mfg][nfg][j] + bb) * sc;
            }
        }
    }
}

// ---------------- fallback (ws too small): 128x128 reg-staged fp32 GEMM ----------------
__global__ __launch_bounds__(256, 2) void role_gemm_fb(
    const float* __restrict__ Ap, const float* __restrict__ Bp,
    const float* __restrict__ onehot, const float* __restrict__ bias,
    const float* __restrict__ scales, float* __restrict__ out)
{
    constexpr int BK = 32;
    constexpr int NT = DDIM / BK;
    constexpr int ROWB = BK * 2 + 16;   // 80 B padded rows
    constexpr int TILEB = 128 * ROWB;
    __shared__ char lds[2 * 2 * 128 * 80];

    const unsigned tid = threadIdx.x;
    const int l = tid & 63;
    const int w = tid >> 6;
    const int wm = w >> 1, wn = w & 1;
    const int fr = l & 15, fq = l >> 4;

    int bid = blockIdx.x;
    int swz = (bid & 7) * 256 + (bid >> 3);
    int batch = swz >> 8;
    int tt = swz & 255;
    int row0 = (tt >> 4) * 128;
    int n0 = (tt & 15) * 128;

    int role = 0;
    #pragma unroll
    for (int r = 1; r < RDIM; ++r) role = (onehot[batch * RDIM + r] > 0.5f) ? r : role;

    f32x4 acc[4][4];
    #pragma unroll
    for (int a = 0; a < 4; ++a)
        #pragma unroll
        for (int b2 = 0; b2 < 4; ++b2)
            #pragma unroll
            for (int r = 0; r < 4; ++r) acc[a][b2][r] = 0.0f;

    auto compute = [&](int p) {
        const char* as = lds + p * (2 * TILEB);
        const char* bs = as + TILEB;
        bf16x8 af[4], bf[4];
        #pragma unroll
        for (int a = 0; a < 4; ++a)
            af[a] = *reinterpret_cast<const bf16x8*>(as + (wm * 64 + a * 16 + fr) * ROWB + fq * 16);
        #pragma unroll
        for (int b2 = 0; b2 < 4; ++b2)
            bf[b2] = *reinterpret_cast<const bf16x8*>(bs + (wn * 64 + b2 * 16 + fr) * ROWB + fq * 16);
        #pragma unroll
        for (int a = 0; a < 4; ++a)
            #pragma unroll
            for (int b2 = 0; b2 < 4; ++b2)
                acc[a][b2] = __builtin_amdgcn_mfma_f32_16x16x32_bf16(af[a], bf[b2], acc[a][b2], 0, 0, 0);
    };

    const float* A = Ap + (size_t)batch * SDIM * DDIM;
    const float* Bb = Bp + (size_t)role * DDIM * DDIM;
    const int am = (int)(tid >> 3);
    const int ak = (int)(tid & 7) * 4;
    const int bn = (int)(tid & 127);
    const int bk0 = (int)(tid >> 7) * 4;

    float4 ar[4];
    float br[16];
    auto loadregs = [&](int k0) {
        #pragma unroll
        for (int i = 0; i < 4; ++i)
            ar[i] = *reinterpret_cast<const float4*>(A + (size_t)(row0 + am + 32 * i) * DDIM + k0 + ak);
        #pragma unroll
        for (int i = 0; i < 4; ++i)
            #pragma unroll
            for (int j = 0; j < 4; ++j)
                br[i * 4 + j] = Bb[(size_t)(k0 + bk0 + 8 * i + j) * DDIM + n0 + bn];
    };
    auto writelds = [&](int p) {
        char* as = lds + p * (2 * TILEB);
        char* bs = as + TILEB;
        #pragma unroll
        for (int i = 0; i < 4; ++i) {
            uint2 u;
            u.x = pack2(ar[i].x, ar[i].y);
            u.y = pack2(ar[i].z, ar[i].w);
            *reinterpret_cast<uint2*>(as + (am + 32 * i) * ROWB + ak * 2) = u;
        }
        #pragma unroll
        for (int i = 0; i < 4; ++i) {
            uint2 u;
            u.x = pack2(br[i * 4 + 0], br[i * 4 + 1]);
            u.y = pack2(br[i * 4 + 2], br[i * 4 + 3]);
            *reinterpret_cast<uint2*>(bs + bn * ROWB + (bk0 + 8 * i) * 2) = u;
        }
    };

    loadregs(0);
    writelds(0);
    __syncthreads();
    for (int t = 0; t < NT; ++t) {
        if (t + 1 < NT) loadregs((t + 1) * BK);
        compute(t & 1);
        if (t + 1 < NT) writelds((t + 1) & 1);
        __syncthreads();
    }

    float sc = scales[role];
    const float* bp2 = bias + (size_t)role * DDIM;
    float* outb = out + ((size_t)batch * SDIM + row0) * DDIM + n0;
    #pragma unroll
    for (int a = 0; a < 4; ++a) {
        #pragma unroll
        for (int b2 = 0; b2 < 4; ++b2) {
            int col = wn * 64 + b2 * 16 + fr;
            float bb = bp2[n0 + col];
            #pragma unroll
            for (int r = 0; r < 4; ++r) {
                int row = wm * 64 + a * 16 + fq * 4 + r;
                outb[(size_t)row * DDIM + col] = fast_tanh(acc[a][b2][r] + bb) * sc;
            }
        }
    }
}

extern "C" void kernel_launch(void* const* d_in, const int* in_sizes, int n_in,
                              void* d_out, int out_size, void* d_ws, size_t ws_size,
                              hipStream_t stream) {
    const float* hidden = (const float*)d_in[0];   // [B,S,D]
    const float* onehot = (const float*)d_in[1];   // [B,R]
    const float* W      = (const float*)d_in[2];   // [R,D,D]
    const float* bias   = (const float*)d_in[3];   // [R,D]
    const float* scales = (const float*)d_in[4];   // [R]
    float* out = (float*)d_out;

    const size_t needH = (size_t)BDIM * SDIM * DDIM * 2;   // 64 MiB
    const size_t needW = (size_t)RDIM * DDIM * DDIM * 2;   // 32 MiB

    if (d_ws != nullptr && ws_size >= needH + needW) {
        unsigned short* Hbf = (unsigned short*)d_ws;
        unsigned short* Wt  = (unsigned short*)((char*)d_ws + needH);
        cvt_h_kernel<<<2048, 256, 0, stream>>>(hidden, Hbf, BDIM * SDIM * DDIM / 8);
        cvt_wt_kernel<<<dim3(DDIM / 32, DDIM / 32, RDIM), dim3(32, 8), 0, stream>>>(W, Wt);
        role_gemm8<<<512, 512, 131072, stream>>>(Hbf, Wt, onehot, bias, scales, out);
    } else {
        role_gemm_fb<<<2048, 256, 0, stream>>>(hidden, W, onehot, bias, scales, out);
    }
}

// Round 3
// 403.805 us; speedup vs baseline: 1.1600x; 1.0021x over previous
//
#include <hip/hip_runtime.h>
#include <stdint.h>

// RoleModulator: out[b,s,e] = tanh( sum_d H[b,s,d]*W[role_b,d,e] + bias[role_b,e] ) * scale[role_b]
// B=8, S=2048, D=2048, R=4. bf16 MFMA 16x16x32, fp32 accum.
// Fast path: fp32->bf16 pre-convert (H straight, W transposed full-line), then
// 256x256 8-phase pipelined GEMM (T1 XCD swizzle, T2 LDS xor-swizzle, T3/T4
// counted vmcnt, T5 setprio). Race-free stage rotation: each half-tile is
// staged strictly after its last LDS read phase (barrier-separated).

#define BDIM 8
#define SDIM 2048
#define DDIM 2048
#define RDIM 4

typedef __attribute__((ext_vector_type(8))) short bf16x8;   // 8 bf16 (4 VGPRs)
typedef __attribute__((ext_vector_type(4))) float f32x4;    // MFMA accumulator
typedef unsigned int uint32;

__device__ __forceinline__ unsigned short f2bf(float f) {
    uint32 u = __float_as_uint(f);
    u += 0x7fffu + ((u >> 16) & 1u);   // round-to-nearest-even
    return (unsigned short)(u >> 16);
}
__device__ __forceinline__ uint32 pack2(float lo, float hi) {
    return (uint32)f2bf(lo) | ((uint32)f2bf(hi) << 16);
}
// overflow-safe fast tanh: t = sign(x) * (1-e)/(1+e), e = exp(-2|x|) in (0,1]
__device__ __forceinline__ float fast_tanh(float x) {
    float ax = __builtin_fabsf(x);
    float e = __expf(-2.0f * ax);
    float t = (1.0f - e) * __builtin_amdgcn_rcpf(1.0f + e);
    return __builtin_copysignf(t, x);
}

// ---------------- pre-conversion kernels ----------------

// H fp32 -> bf16 straight copy, 32B loads / 16B stores per lane
__global__ __launch_bounds__(256) void cvt_h_kernel(const float* __restrict__ h,
                                                    unsigned short* __restrict__ o, int n8) {
    int i = blockIdx.x * blockDim.x + threadIdx.x;
    int stride = gridDim.x * blockDim.x;
    for (; i < n8; i += stride) {
        float4 v0 = reinterpret_cast<const float4*>(h)[2 * i];
        float4 v1 = reinterpret_cast<const float4*>(h)[2 * i + 1];
        uint4 p;
        p.x = pack2(v0.x, v0.y);
        p.y = pack2(v0.z, v0.w);
        p.z = pack2(v1.x, v1.y);
        p.w = pack2(v1.z, v1.w);
        reinterpret_cast<uint4*>(o)[i] = p;
    }
}

// W[r][d][e] fp32 -> Wt[r][e][d] bf16. 64x64 tiles: 256B coalesced reads,
// 128B full-line writes. LDS [64][65] ushort: <=2-way on both sides (free).
__global__ __launch_bounds__(256) void cvt_wt_kernel(const float* __restrict__ w,
                                                     unsigned short* __restrict__ o) {
    __shared__ unsigned short tile[64][65];
    int r = blockIdx.z;
    int e0 = blockIdx.x * 64, d0 = blockIdx.y * 64;
    const float* wr = w + (size_t)r * DDIM * DDIM;
    unsigned short* orr = o + (size_t)r * DDIM * DDIM;
    int tx = threadIdx.x & 63, ty = threadIdx.x >> 6;   // 64 x 4
    #pragma unroll
    for (int i = ty; i < 64; i += 4)
        tile[i][tx] = f2bf(wr[(size_t)(d0 + i) * DDIM + e0 + tx]);
    __syncthreads();
    #pragma unroll
    for (int i = ty; i < 64; i += 4)
        orr[(size_t)(e0 + i) * DDIM + d0 + tx] = tile[tx][i];
}

// ---------------- 256x256 8-phase GEMM (fast path) ----------------
// 512 threads = 8 waves (2M x 4N); per-wave 128x64 output = 8x4 frags 16x16.
// BK=64. LDS: 2 buffers x (A[256][64] + B[256][64]) bf16 = 128KB dynamic.
// Swizzle: logical byte P -> lds byte P ^ ((row&7)<<4); global_load_lds writes
// linearly, so the SOURCE k-chunk is pre-permuted (kc ^ (row&7)); reads XOR.
// Stage rotation (race-free): A-h1(t+1)@q0, B-h0(t+2)@q2, B-h1+A-h0(t+2)@q3.
// Last reads: B-halves@q1, A-h0@q2(wm0), A-h1@q2(wm1) -> every stage lands
// strictly after the staged region's last read, with barriers between.
// FIFO: end-of-tile vmcnt(6) drains exactly tile-(t+1)'s 8 loads.

__global__ __launch_bounds__(512, 2) void role_gemm8(
    const unsigned short* __restrict__ Hb,   // [B,S,D] bf16
    const unsigned short* __restrict__ Wt,   // [R,E,D] bf16
    const float* __restrict__ onehot,        // [B,R]
    const float* __restrict__ bias,          // [R,D]
    const float* __restrict__ scales,        // [R]
    float* __restrict__ out)                 // [B,S,D] fp32
{
    constexpr int NT = DDIM / 64;            // 32 K-tiles
    extern __shared__ char lds[];

    const int tid = threadIdx.x;
    const int l = tid & 63;
    const int wv = tid >> 6;      // 0..7
    const int wm = wv >> 2;       // 0..1  (M half)
    const int wn = wv & 3;        // 0..3  (N quarter)
    const int fr = l & 15;
    const int fq = l >> 4;
    const int l7 = l & 7;
    const int colx0 = ((fq ^ l7) << 4);          // ks=0 swizzled 16B col
    const int colx1 = (((4 + fq) ^ l7) << 4);    // ks=1

    // T1: XCD-bijective swizzle (512 blocks, 512%8==0); each XCD owns one batch
    int bid = blockIdx.x;
    int swz = (bid & 7) * 64 + (bid >> 3);
    int batch = swz >> 6;
    int tt = swz & 63;
    int row0 = (tt >> 3) * 256;
    int n0 = (tt & 7) * 256;

    int role = 0;
    #pragma unroll
    for (int r = 1; r < RDIM; ++r) role = (onehot[batch * RDIM + r] > 0.5f) ? r : role;

    const unsigned short* A = Hb + (size_t)batch * SDIM * DDIM;
    const unsigned short* Bw = Wt + (size_t)role * DDIM * DDIM;

    f32x4 acc[8][4];
    #pragma unroll
    for (int m = 0; m < 8; ++m)
        #pragma unroll
        for (int n = 0; n < 4; ++n)
            #pragma unroll
            for (int j = 0; j < 4; ++j) acc[m][n][j] = 0.0f;

    bf16x8 aR[4][2];      // current m-quadrant A frags
    bf16x8 bQ0[2][2];     // n-quadrant 0 B frags (live across the tile)
    bf16x8 bQ1[2][2];     // n-quadrant 1

    // stage one half-tile: kind 0=A,1=B; buffer d; half h; K-tile T. 2 loads/thread.
    auto stage_half = [&](int d, int kind, int h, int T) {
        const unsigned short* sb = kind ? Bw : A;
        int rowbase = (kind ? n0 : row0) + h * 128;
        char* base = lds + d * 65536 + kind * 32768 + h * 16384;
        #pragma unroll
        for (int j = 0; j < 2; ++j) {
            int c = j * 512 + tid;               // 16B chunk 0..1023
            int r = c >> 3, kc = c & 7;
            int kcs = kc ^ (r & 7);              // inverse-swizzled source k-chunk
            const unsigned short* src = sb + (size_t)(rowbase + r) * DDIM + T * 64 + kcs * 8;
            char* dst = base + ((j * 512 + (tid & 0x1C0)) << 4);   // wave-uniform base
            __builtin_amdgcn_global_load_lds(
                (const __attribute__((address_space(1))) void*)src,
                (__attribute__((address_space(3))) void*)dst, 16, 0, 0);
        }
    };

    auto loadA = [&](int d, int mq) {
        const char* ab = lds + d * 65536;
        #pragma unroll
        for (int mf = 0; mf < 4; ++mf) {
            int rb = (wm * 128 + (mq * 4 + mf) * 16 + fr) * 128;
            aR[mf][0] = *reinterpret_cast<const bf16x8*>(ab + rb + colx0);
            aR[mf][1] = *reinterpret_cast<const bf16x8*>(ab + rb + colx1);
        }
    };
    auto loadB = [&](int d, int nq, bf16x8 (&bR)[2][2]) {
        const char* bb = lds + d * 65536 + 32768;
        #pragma unroll
        for (int nf = 0; nf < 2; ++nf) {
            int rb = (wn * 64 + (nq * 2 + nf) * 16 + fr) * 128;
            bR[nf][0] = *reinterpret_cast<const bf16x8*>(bb + rb + colx0);
            bR[nf][1] = *reinterpret_cast<const bf16x8*>(bb + rb + colx1);
        }
    };
    auto mmaQ = [&](int mq, int nq, bf16x8 (&bR)[2][2]) {
        __builtin_amdgcn_s_setprio(1);
        #pragma unroll
        for (int mf = 0; mf < 4; ++mf)
            #pragma unroll
            for (int nf = 0; nf < 2; ++nf)
                #pragma unroll
                for (int ks = 0; ks < 2; ++ks)
                    acc[mq * 4 + mf][nq * 2 + nf] = __builtin_amdgcn_mfma_f32_16x16x32_bf16(
                        aR[mf][ks], bR[nf][ks], acc[mq * 4 + mf][nq * 2 + nf], 0, 0, 0);
        __builtin_amdgcn_s_setprio(0);
    };

    // ---- prologue: tile0 full (8 loads), then tile1 {B0,B1,A0} (6 loads).
    stage_half(0, 1, 0, 0); stage_half(0, 1, 1, 0);
    stage_half(0, 0, 0, 0); stage_half(0, 0, 1, 0);
    stage_half(1, 1, 0, 1); stage_half(1, 1, 1, 1);
    stage_half(1, 0, 0, 1);
    asm volatile("s_waitcnt vmcnt(6)" ::: "memory");   // tile0's 8 loads landed
    __builtin_amdgcn_s_barrier();

    // ---- main loop: 4 phases per K-tile
    for (int t = 0; t < NT; ++t) {
        const int d = t & 1, e = d ^ 1;
        // q0: read A(mq0)+B(nq0); stage A-h1(t+1) -> buf e (its region last read q2(t-1))
        loadA(d, 0);
        loadB(d, 0, bQ0);
        if (t + 1 < NT) stage_half(e, 0, 1, t + 1);
        __builtin_amdgcn_s_barrier();
        asm volatile("s_waitcnt lgkmcnt(0)" ::: "memory");
        mmaQ(0, 0, bQ0);
        __builtin_amdgcn_s_barrier();
        // q1: read B(nq1) — last reads of both B halves this tile; no stage
        loadB(d, 1, bQ1);
        __builtin_amdgcn_s_barrier();
        asm volatile("s_waitcnt lgkmcnt(0)" ::: "memory");
        mmaQ(0, 1, bQ1);
        __builtin_amdgcn_s_barrier();
        // q2: read A(mq1) — last reads of both A halves; stage B-h0(t+2) -> buf d
        loadA(d, 1);
        if (t + 2 < NT) stage_half(d, 1, 0, t + 2);
        __builtin_amdgcn_s_barrier();
        asm volatile("s_waitcnt lgkmcnt(0)" ::: "memory");
        mmaQ(1, 1, bQ1);
        __builtin_amdgcn_s_barrier();
        // q3: no reads; stage B-h1(t+2) + A-h0(t+2) -> buf d; MFMA reuses bQ0 regs
        if (t + 2 < NT) { stage_half(d, 1, 1, t + 2); stage_half(d, 0, 0, t + 2); }
        __builtin_amdgcn_s_barrier();
        mmaQ(1, 0, bQ0);
        // counted drain: leaves exactly tile-(t+2)'s 6 early loads in flight
        if (t < NT - 2) { asm volatile("s_waitcnt vmcnt(6)" ::: "memory"); }
        else            { asm volatile("s_waitcnt vmcnt(0)" ::: "memory"); }
        __builtin_amdgcn_s_barrier();
    }

    // ---- epilogue: bias + tanh + scale, fp32 store
    float sc = scales[role];
    const float* bp = bias + (size_t)role * DDIM + n0 + wn * 64;
    float bb[4];
    #pragma unroll
    for (int nfg = 0; nfg < 4; ++nfg) bb[nfg] = bp[nfg * 16 + fr];
    float* ob = out + ((size_t)batch * SDIM + row0 + wm * 128) * DDIM + n0 + wn * 64;
    #pragma unroll
    for (int mfg = 0; mfg < 8; ++mfg) {
        #pragma unroll
        for (int nfg = 0; nfg < 4; ++nfg) {
            int col = nfg * 16 + fr;
            #pragma unroll
            for (int j = 0; j < 4; ++j) {
                int row = mfg * 16 + fq * 4 + j;
                ob[(size_t)row * DDIM + col] = fast_tanh(acc[mfg][nfg][j] + bb[nfg]) * sc;
            }
        }
    }
}

// ---------------- fallback (ws too small): 128x128 reg-staged fp32 GEMM ----------------
__global__ __launch_bounds__(256, 2) void role_gemm_fb(
    const float* __restrict__ Ap, const float* __restrict__ Bp,
    const float* __restrict__ onehot, const float* __restrict__ bias,
    const float* __restrict__ scales, float* __restrict__ out)
{
    constexpr int BK = 32;
    constexpr int NT = DDIM / BK;
    constexpr int ROWB = BK * 2 + 16;   // 80 B padded rows
    constexpr int TILEB = 128 * ROWB;
    __shared__ char lds[2 * 2 * 128 * 80];

    const unsigned tid = threadIdx.x;
    const int l = tid & 63;
    const int w = tid >> 6;
    const int wm = w >> 1, wn = w & 1;
    const int fr = l & 15, fq = l >> 4;

    int bid = blockIdx.x;
    int swz = (bid & 7) * 256 + (bid >> 3);
    int batch = swz >> 8;
    int tt = swz & 255;
    int row0 = (tt >> 4) * 128;
    int n0 = (tt & 15) * 128;

    int role = 0;
    #pragma unroll
    for (int r = 1; r < RDIM; ++r) role = (onehot[batch * RDIM + r] > 0.5f) ? r : role;

    f32x4 acc[4][4];
    #pragma unroll
    for (int a = 0; a < 4; ++a)
        #pragma unroll
        for (int b2 = 0; b2 < 4; ++b2)
            #pragma unroll
            for (int r = 0; r < 4; ++r) acc[a][b2][r] = 0.0f;

    auto compute = [&](int p) {
        const char* as = lds + p * (2 * TILEB);
        const char* bs = as + TILEB;
        bf16x8 af[4], bf[4];
        #pragma unroll
        for (int a = 0; a < 4; ++a)
            af[a] = *reinterpret_cast<const bf16x8*>(as + (wm * 64 + a * 16 + fr) * ROWB + fq * 16);
        #pragma unroll
        for (int b2 = 0; b2 < 4; ++b2)
            bf[b2] = *reinterpret_cast<const bf16x8*>(bs + (wn * 64 + b2 * 16 + fr) * ROWB + fq * 16);
        #pragma unroll
        for (int a = 0; a < 4; ++a)
            #pragma unroll
            for (int b2 = 0; b2 < 4; ++b2)
                acc[a][b2] = __builtin_amdgcn_mfma_f32_16x16x32_bf16(af[a], bf[b2], acc[a][b2], 0, 0, 0);
    };

    const float* A = Ap + (size_t)batch * SDIM * DDIM;
    const float* Bb = Bp + (size_t)role * DDIM * DDIM;
    const int am = (int)(tid >> 3);
    const int ak = (int)(tid & 7) * 4;
    const int bn = (int)(tid & 127);
    const int bk0 = (int)(tid >> 7) * 4;

    float4 ar[4];
    float br[16];
    auto loadregs = [&](int k0) {
        #pragma unroll
        for (int i = 0; i < 4; ++i)
            ar[i] = *reinterpret_cast<const float4*>(A + (size_t)(row0 + am + 32 * i) * DDIM + k0 + ak);
        #pragma unroll
        for (int i = 0; i < 4; ++i)
            #pragma unroll
            for (int j = 0; j < 4; ++j)
                br[i * 4 + j] = Bb[(size_t)(k0 + bk0 + 8 * i + j) * DDIM + n0 + bn];
    };
    auto writelds = [&](int p) {
        char* as = lds + p * (2 * TILEB);
        char* bs = as + TILEB;
        #pragma unroll
        for (int i = 0; i < 4; ++i) {
            uint2 u;
            u.x = pack2(ar[i].x, ar[i].y);
            u.y = pack2(ar[i].z, ar[i].w);
            *reinterpret_cast<uint2*>(as + (am + 32 * i) * ROWB + ak * 2) = u;
        }
        #pragma unroll
        for (int i = 0; i < 4; ++i) {
            uint2 u;
            u.x = pack2(br[i * 4 + 0], br[i * 4 + 1]);
            u.y = pack2(br[i * 4 + 2], br[i * 4 + 3]);
            *reinterpret_cast<uint2*>(bs + bn * ROWB + (bk0 + 8 * i) * 2) = u;
        }
    };

    loadregs(0);
    writelds(0);
    __syncthreads();
    for (int t = 0; t < NT; ++t) {
        if (t + 1 < NT) loadregs((t + 1) * BK);
        compute(t & 1);
        if (t + 1 < NT) writelds((t + 1) & 1);
        __syncthreads();
    }

    float sc = scales[role];
    const float* bp2 = bias + (size_t)role * DDIM;
    float* outb = out + ((size_t)batch * SDIM + row0) * DDIM + n0;
    #pragma unroll
    for (int a = 0; a < 4; ++a) {
        #pragma unroll
        for (int b2 = 0; b2 < 4; ++b2) {
            int col = wn * 64 + b2 * 16 + fr;
            float bb = bp2[n0 + col];
            #pragma unroll
            for (int r = 0; r < 4; ++r) {
                int row = wm * 64 + a * 16 + fq * 4 + r;
                outb[(size_t)row * DDIM + col] = fast_tanh(acc[a][b2][r] + bb) * sc;
            }
        }
    }
}

extern "C" void kernel_launch(void* const* d_in, const int* in_sizes, int n_in,
                              void* d_out, int out_size, void* d_ws, size_t ws_size,
                              hipStream_t stream) {
    const float* hidden = (const float*)d_in[0];   // [B,S,D]
    const float* onehot = (const float*)d_in[1];   // [B,R]
    const float* W      = (const float*)d_in[2];   // [R,D,D]
    const float* bias   = (const float*)d_in[3];   // [R,D]
    const float* scales = (const float*)d_in[4];   // [R]
    float* out = (float*)d_out;

    const size_t needH = (size_t)BDIM * SDIM * DDIM * 2;   // 64 MiB
    const size_t needW = (size_t)RDIM * DDIM * DDIM * 2;   // 32 MiB

    if (d_ws != nullptr && ws_size >= needH + needW) {
        unsigned short* Hbf = (unsigned short*)d_ws;
        unsigned short* Wt  = (unsigned short*)((char*)d_ws + needH);
        cvt_h_kernel<<<2048, 256, 0, stream>>>(hidden, Hbf, BDIM * SDIM * DDIM / 8);
        cvt_wt_kernel<<<dim3(DDIM / 64, DDIM / 64, RDIM), dim3(256), 0, stream>>>(W, Wt);
        role_gemm8<<<512, 512, 131072, stream>>>(Hbf, Wt, onehot, bias, scales, out);
    } else {
        role_gemm_fb<<<2048, 256, 0, stream>>>(hidden, W, onehot, bias, scales, out);
    }
}

// Round 5
// 398.812 us; speedup vs baseline: 1.1745x; 1.0125x over previous
//
#include <hip/hip_runtime.h>
#include <stdint.h>

// RoleModulator: out[b,s,e] = tanh( sum_d H[b,s,d]*W[role_b,d,e] + bias[role_b,e] ) * scale[role_b]
// B=8, S=2048, D=2048, R=4. bf16 MFMA 16x16x32, fp32 accum.
// Fast path: fp32->bf16 pre-convert, then 256x256 BK=64 GEMM with
// READ-AHEAD counted-lgkmcnt schedule: phase p issues ds_reads for phase p+1,
// MFMA(p) waits lgkmcnt(N) for the older group only -> LDS drain overlaps MFMA.
// Quadrant order q0:(m0,n0) q1:(m1,n0) q2:(m0,n1) q3:(m1,n1); reads 8/4/4/8.
// Cross-tile reads (B0',A0') gated by vmcnt(4)+s_barrier (all waves' stages
// visible). Stages: B(t+2)@q2, A(t+2)@q3 - strictly after last reads @q0/q1.

#define BDIM 8
#define SDIM 2048
#define DDIM 2048
#define RDIM 4

typedef __attribute__((ext_vector_type(8))) short bf16x8;   // 8 bf16 (4 VGPRs)
typedef __attribute__((ext_vector_type(4))) float f32x4;    // MFMA accumulator
typedef unsigned int uint32;

__device__ __forceinline__ unsigned short f2bf(float f) {
    uint32 u = __float_as_uint(f);
    u += 0x7fffu + ((u >> 16) & 1u);   // round-to-nearest-even
    return (unsigned short)(u >> 16);
}
__device__ __forceinline__ uint32 pack2(float lo, float hi) {
    return (uint32)f2bf(lo) | ((uint32)f2bf(hi) << 16);
}
// overflow-safe fast tanh: t = sign(x) * (1-e)/(1+e), e = exp(-2|x|) in (0,1]
__device__ __forceinline__ float fast_tanh(float x) {
    float ax = __builtin_fabsf(x);
    float e = __expf(-2.0f * ax);
    float t = (1.0f - e) * __builtin_amdgcn_rcpf(1.0f + e);
    return __builtin_copysignf(t, x);
}

// ---------------- pre-conversion kernels ----------------

__global__ __launch_bounds__(256) void cvt_h_kernel(const float* __restrict__ h,
                                                    unsigned short* __restrict__ o, int n8) {
    int i = blockIdx.x * blockDim.x + threadIdx.x;
    int stride = gridDim.x * blockDim.x;
    for (; i < n8; i += stride) {
        float4 v0 = reinterpret_cast<const float4*>(h)[2 * i];
        float4 v1 = reinterpret_cast<const float4*>(h)[2 * i + 1];
        uint4 p;
        p.x = pack2(v0.x, v0.y);
        p.y = pack2(v0.z, v0.w);
        p.z = pack2(v1.x, v1.y);
        p.w = pack2(v1.z, v1.w);
        reinterpret_cast<uint4*>(o)[i] = p;
    }
}

// W[r][d][e] fp32 -> Wt[r][e][d] bf16. 64x64 tiles, coalesced both sides.
__global__ __launch_bounds__(256) void cvt_wt_kernel(const float* __restrict__ w,
                                                     unsigned short* __restrict__ o) {
    __shared__ unsigned short tile[64][65];
    int r = blockIdx.z;
    int e0 = blockIdx.x * 64, d0 = blockIdx.y * 64;
    const float* wr = w + (size_t)r * DDIM * DDIM;
    unsigned short* orr = o + (size_t)r * DDIM * DDIM;
    int tx = threadIdx.x & 63, ty = threadIdx.x >> 6;   // 64 x 4
    #pragma unroll
    for (int i = ty; i < 64; i += 4)
        tile[i][tx] = f2bf(wr[(size_t)(d0 + i) * DDIM + e0 + tx]);
    __syncthreads();
    #pragma unroll
    for (int i = ty; i < 64; i += 4)
        orr[(size_t)(e0 + i) * DDIM + d0 + tx] = tile[tx][i];
}

// ---------------- 256x256 read-ahead GEMM (fast path) ----------------
__global__ __launch_bounds__(512, 2) void role_gemm8b(
    const unsigned short* __restrict__ Hb,   // [B,S,D] bf16
    const unsigned short* __restrict__ Wt,   // [R,E,D] bf16
    const float* __restrict__ onehot,        // [B,R]
    const float* __restrict__ bias,          // [R,D]
    const float* __restrict__ scales,        // [R]
    float* __restrict__ out)                 // [B,S,D] fp32
{
    constexpr int NT = DDIM / 64;            // 32 K-tiles
    extern __shared__ char lds[];

    const int tid = threadIdx.x;
    const int l = tid & 63;
    const int wv = tid >> 6;      // 0..7
    const int wm = wv >> 2;       // 0..1  (M half)
    const int wn = wv & 3;        // 0..3  (N quarter)
    const int fr = l & 15;
    const int fq = l >> 4;
    const int l7 = l & 7;
    const int colx0 = ((fq ^ l7) << 4);          // ks=0 swizzled 16B col
    const int colx1 = (((4 + fq) ^ l7) << 4);    // ks=1

    // T1: XCD-bijective swizzle (512 blocks, 512%8==0); each XCD owns one batch
    int bid = blockIdx.x;
    int swz = (bid & 7) * 64 + (bid >> 3);
    int batch = swz >> 6;
    int tt = swz & 63;
    int row0 = (tt >> 3) * 256;
    int n0 = (tt & 7) * 256;

    int role = 0;
    #pragma unroll
    for (int r = 1; r < RDIM; ++r) role = (onehot[batch * RDIM + r] > 0.5f) ? r : role;

    const unsigned short* A = Hb + (size_t)batch * SDIM * DDIM;
    const unsigned short* Bw = Wt + (size_t)role * DDIM * DDIM;

    f32x4 acc[8][4];
    #pragma unroll
    for (int m = 0; m < 8; ++m)
        #pragma unroll
        for (int n = 0; n < 4; ++n)
            #pragma unroll
            for (int j = 0; j < 4; ++j) acc[m][n][j] = 0.0f;

    bf16x8 aE[4][2];   // A m-frags 0-3 (rows wm*128 + 0..63)
    bf16x8 aO[4][2];   // A m-frags 4-7 (rows wm*128 + 64..127)
    bf16x8 bQ0[2][2];  // B n-frags 0-1 (cols wn*64 + 0..31)
    bf16x8 bQ1[2][2];  // B n-frags 2-3 (cols wn*64 + 32..63)

    // stage one half-tile: kind 0=A,1=B; buffer d; half h; K-tile T. 2 loads/thread.
    auto stage_half = [&](int d, int kind, int h, int T) {
        const unsigned short* sb = kind ? Bw : A;
        int rowbase = (kind ? n0 : row0) + h * 128;
        char* base = lds + d * 65536 + kind * 32768 + h * 16384;
        #pragma unroll
        for (int j = 0; j < 2; ++j) {
            int c = j * 512 + tid;               // 16B chunk 0..1023
            int r = c >> 3, kc = c & 7;
            int kcs = kc ^ (r & 7);              // inverse-swizzled source k-chunk
            const unsigned short* src = sb + (size_t)(rowbase + r) * DDIM + T * 64 + kcs * 8;
            char* dst = base + ((j * 512 + (tid & 0x1C0)) << 4);   // wave-uniform base
            __builtin_amdgcn_global_load_lds(
                (const __attribute__((address_space(1))) void*)src,
                (__attribute__((address_space(3))) void*)dst, 16, 0, 0);
        }
    };
    auto stageB = [&](int d, int T) { stage_half(d, 1, 0, T); stage_half(d, 1, 1, T); };
    auto stageA = [&](int d, int T) { stage_half(d, 0, 0, T); stage_half(d, 0, 1, T); };

    auto readA = [&](int d, bf16x8 (&dst)[4][2], int mq) {
        const char* ab = lds + d * 65536;
        #pragma unroll
        for (int mf = 0; mf < 4; ++mf) {
            int rb = (wm * 128 + (mq * 4 + mf) * 16 + fr) * 128;
            dst[mf][0] = *reinterpret_cast<const bf16x8*>(ab + rb + colx0);
            dst[mf][1] = *reinterpret_cast<const bf16x8*>(ab + rb + colx1);
        }
    };
    auto readB = [&](int d, bf16x8 (&dst)[2][2], int nq) {
        const char* bb = lds + d * 65536 + 32768;
        #pragma unroll
        for (int nf = 0; nf < 2; ++nf) {
            int rb = (wn * 64 + (nq * 2 + nf) * 16 + fr) * 128;
            dst[nf][0] = *reinterpret_cast<const bf16x8*>(bb + rb + colx0);
            dst[nf][1] = *reinterpret_cast<const bf16x8*>(bb + rb + colx1);
        }
    };
    auto mmaQ = [&](bf16x8 (&a)[4][2], bf16x8 (&b)[2][2], int mq, int nq) {
        __builtin_amdgcn_s_setprio(1);
        #pragma unroll
        for (int mf = 0; mf < 4; ++mf)
            #pragma unroll
            for (int nf = 0; nf < 2; ++nf)
                #pragma unroll
                for (int ks = 0; ks < 2; ++ks)
                    acc[mq * 4 + mf][nq * 2 + nf] = __builtin_amdgcn_mfma_f32_16x16x32_bf16(
                        a[mf][ks], b[nf][ks], acc[mq * 4 + mf][nq * 2 + nf], 0, 0, 0);
        __builtin_amdgcn_s_setprio(0);
    };

    // ---- prologue: tile0 -> buf0 (8 loads), tile1 -> buf1 (8 loads), FIFO B-then-A
    stageB(0, 0); stageA(0, 0);
    stageB(1, 1); stageA(1, 1);
    asm volatile("s_waitcnt vmcnt(8)" ::: "memory");   // tile0 landed; {B(1),A(1)} in flight
    __builtin_amdgcn_s_barrier();
    readB(0, bQ0, 0);        // 4 ds_reads
    readA(0, aE, 0);         // 8 ds_reads  (lgkm outstanding = 12, steady invariant)

    // ---- main loop: 4 phases per K-tile, read-ahead by one phase
    for (int t = 0; t < NT; ++t) {
        const int d = t & 1, e = d ^ 1;
        // q0: read A1(t) -> aO (feeds q1); MFMA (m0,n0) on aE,bQ0
        readA(d, aO, 1);                                   // 8 reads; outstanding 12+8
        asm volatile("s_waitcnt lgkmcnt(8)" ::: "memory"); // older 12 (B0,A0) done
        __builtin_amdgcn_sched_barrier(0);
        mmaQ(aE, bQ0, 0, 0);
        __builtin_amdgcn_s_barrier();
        // q1: read B1(t) -> bQ1 (feeds q2); MFMA (m1,n0) on aO,bQ0
        readB(d, bQ1, 1);                                  // 4 reads; outstanding 8+4
        asm volatile("s_waitcnt lgkmcnt(4)" ::: "memory"); // A1 done
        __builtin_amdgcn_sched_barrier(0);
        mmaQ(aO, bQ0, 1, 0);
        __builtin_amdgcn_s_barrier();
        // q2: gate B(t+1) landed; read B0(t+1) -> bQ0; stage B(t+2); MFMA (m0,n1)
        if (t + 1 < NT) {
            asm volatile("s_waitcnt vmcnt(4)" ::: "memory");   // B(t+1) stages done (own)
            __builtin_amdgcn_s_barrier();                      // ...and everyone's
            readB(e, bQ0, 0);                                  // 4 reads
        }
        if (t + 2 < NT) stageB(d, t + 2);
        if (t + 1 < NT) { asm volatile("s_waitcnt lgkmcnt(4)" ::: "memory"); }
        else            { asm volatile("s_waitcnt lgkmcnt(0)" ::: "memory"); }
        __builtin_amdgcn_sched_barrier(0);                 // B1 done
        mmaQ(aE, bQ1, 0, 1);
        __builtin_amdgcn_s_barrier();
        // q3: gate A(t+1) landed; read A0(t+1) -> aE; stage A(t+2); MFMA (m1,n1)
        if (t + 1 < NT) {
            if (t + 2 < NT) { asm volatile("s_waitcnt vmcnt(4)" ::: "memory"); }
            else            { asm volatile("s_waitcnt vmcnt(0)" ::: "memory"); }
            __builtin_amdgcn_s_barrier();
            readA(e, aE, 0);                                   // 8 reads
        }
        if (t + 2 < NT) stageA(d, t + 2);
        // no lgkm wait: aO (q1-waited), bQ1 (q2-waited) already resolved
        mmaQ(aO, bQ1, 1, 1);
        __builtin_amdgcn_s_barrier();
    }

    // ---- epilogue: bias + tanh + scale, fp32 store
    float sc = scales[role];
    const float* bp = bias + (size_t)role * DDIM + n0 + wn * 64;
    float bb[4];
    #pragma unroll
    for (int nfg = 0; nfg < 4; ++nfg) bb[nfg] = bp[nfg * 16 + fr];
    float* ob = out + ((size_t)batch * SDIM + row0 + wm * 128) * DDIM + n0 + wn * 64;
    #pragma unroll
    for (int mfg = 0; mfg < 8; ++mfg) {
        #pragma unroll
        for (int nfg = 0; nfg < 4; ++nfg) {
            int col = nfg * 16 + fr;
            #pragma unroll
            for (int j = 0; j < 4; ++j) {
                int row = mfg * 16 + fq * 4 + j;
                ob[(size_t)row * DDIM + col] = fast_tanh(acc[mfg][nfg][j] + bb[nfg]) * sc;
            }
        }
    }
}

// ---------------- fallback (ws too small): 128x128 reg-staged fp32 GEMM ----------------
__global__ __launch_bounds__(256, 2) void role_gemm_fb(
    const float* __restrict__ Ap, const float* __restrict__ Bp,
    const float* __restrict__ onehot, const float* __restrict__ bias,
    const float* __restrict__ scales, float* __restrict__ out)
{
    constexpr int BK = 32;
    constexpr int NT = DDIM / BK;
    constexpr int ROWB = BK * 2 + 16;   // 80 B padded rows
    constexpr int TILEB = 128 * ROWB;
    __shared__ char lds[2 * 2 * 128 * 80];

    const unsigned tid = threadIdx.x;
    const int l = tid & 63;
    const int w = tid >> 6;
    const int wm = w >> 1, wn = w & 1;
    const int fr = l & 15, fq = l >> 4;

    int bid = blockIdx.x;
    int swz = (bid & 7) * 256 + (bid >> 3);
    int batch = swz >> 8;
    int tt = swz & 255;
    int row0 = (tt >> 4) * 128;
    int n0 = (tt & 15) * 128;

    int role = 0;
    #pragma unroll
    for (int r = 1; r < RDIM; ++r) role = (onehot[batch * RDIM + r] > 0.5f) ? r : role;

    f32x4 acc[4][4];
    #pragma unroll
    for (int a = 0; a < 4; ++a)
        #pragma unroll
        for (int b2 = 0; b2 < 4; ++b2)
            #pragma unroll
            for (int r = 0; r < 4; ++r) acc[a][b2][r] = 0.0f;

    auto compute = [&](int p) {
        const char* as = lds + p * (2 * TILEB);
        const char* bs = as + TILEB;
        bf16x8 af[4], bf[4];
        #pragma unroll
        for (int a = 0; a < 4; ++a)
            af[a] = *reinterpret_cast<const bf16x8*>(as + (wm * 64 + a * 16 + fr) * ROWB + fq * 16);
        #pragma unroll
        for (int b2 = 0; b2 < 4; ++b2)
            bf[b2] = *reinterpret_cast<const bf16x8*>(bs + (wn * 64 + b2 * 16 + fr) * ROWB + fq * 16);
        #pragma unroll
        for (int a = 0; a < 4; ++a)
            #pragma unroll
            for (int b2 = 0; b2 < 4; ++b2)
                acc[a][b2] = __builtin_amdgcn_mfma_f32_16x16x32_bf16(af[a], bf[b2], acc[a][b2], 0, 0, 0);
    };

    const float* A = Ap + (size_t)batch * SDIM * DDIM;
    const float* Bb = Bp + (size_t)role * DDIM * DDIM;
    const int am = (int)(tid >> 3);
    const int ak = (int)(tid & 7) * 4;
    const int bn = (int)(tid & 127);
    const int bk0 = (int)(tid >> 7) * 4;

    float4 ar[4];
    float br[16];
    auto loadregs = [&](int k0) {
        #pragma unroll
        for (int i = 0; i < 4; ++i)
            ar[i] = *reinterpret_cast<const float4*>(A + (size_t)(row0 + am + 32 * i) * DDIM + k0 + ak);
        #pragma unroll
        for (int i = 0; i < 4; ++i)
            #pragma unroll
            for (int j = 0; j < 4; ++j)
                br[i * 4 + j] = Bb[(size_t)(k0 + bk0 + 8 * i + j) * DDIM + n0 + bn];
    };
    auto writelds = [&](int p) {
        char* as = lds + p * (2 * TILEB);
        char* bs = as + TILEB;
        #pragma unroll
        for (int i = 0; i < 4; ++i) {
            uint2 u;
            u.x = pack2(ar[i].x, ar[i].y);
            u.y = pack2(ar[i].z, ar[i].w);
            *reinterpret_cast<uint2*>(as + (am + 32 * i) * ROWB + ak * 2) = u;
        }
        #pragma unroll
        for (int i = 0; i < 4; ++i) {
            uint2 u;
            u.x = pack2(br[i * 4 + 0], br[i * 4 + 1]);
            u.y = pack2(br[i * 4 + 2], br[i * 4 + 3]);
            *reinterpret_cast<uint2*>(bs + bn * ROWB + (bk0 + 8 * i) * 2) = u;
        }
    };

    loadregs(0);
    writelds(0);
    __syncthreads();
    for (int t = 0; t < NT; ++t) {
        if (t + 1 < NT) loadregs((t + 1) * BK);
        compute(t & 1);
        if (t + 1 < NT) writelds((t + 1) & 1);
        __syncthreads();
    }

    float sc = scales[role];
    const float* bp2 = bias + (size_t)role * DDIM;
    float* outb = out + ((size_t)batch * SDIM + row0) * DDIM + n0;
    #pragma unroll
    for (int a = 0; a < 4; ++a) {
        #pragma unroll
        for (int b2 = 0; b2 < 4; ++b2) {
            int col = wn * 64 + b2 * 16 + fr;
            float bb = bp2[n0 + col];
            #pragma unroll
            for (int r = 0; r < 4; ++r) {
                int row = wm * 64 + a * 16 + fq * 4 + r;
                outb[(size_t)row * DDIM + col] = fast_tanh(acc[a][b2][r] + bb) * sc;
            }
        }
    }
}

extern "C" void kernel_launch(void* const* d_in, const int* in_sizes, int n_in,
                              void* d_out, int out_size, void* d_ws, size_t ws_size,
                              hipStream_t stream) {
    const float* hidden = (const float*)d_in[0];   // [B,S,D]
    const float* onehot = (const float*)d_in[1];   // [B,R]
    const float* W      = (const float*)d_in[2];   // [R,D,D]
    const float* bias   = (const float*)d_in[3];   // [R,D]
    const float* scales = (const float*)d_in[4];   // [R]
    float* out = (float*)d_out;

    const size_t needH = (size_t)BDIM * SDIM * DDIM * 2;   // 64 MiB
    const size_t needW = (size_t)RDIM * DDIM * DDIM * 2;   // 32 MiB

    if (d_ws != nullptr && ws_size >= needH + needW) {
        unsigned short* Hbf = (unsigned short*)d_ws;
        unsigned short* Wt  = (unsigned short*)((char*)d_ws + needH);
        cvt_h_kernel<<<2048, 256, 0, stream>>>(hidden, Hbf, BDIM * SDIM * DDIM / 8);
        cvt_wt_kernel<<<dim3(DDIM / 64, DDIM / 64, RDIM), dim3(256), 0, stream>>>(W, Wt);
        role_gemm8b<<<512, 512, 131072, stream>>>(Hbf, Wt, onehot, bias, scales, out);
    } else {
        role_gemm_fb<<<2048, 256, 0, stream>>>(hidden, W, onehot, bias, scales, out);
    }
}